// Round 1
// baseline (563.951 us; speedup 1.0000x reference)
//
#include <hip/hip_runtime.h>
#include <hip/hip_bf16.h>
#include <cstdint>

typedef __bf16 bf16;
typedef bf16 bf16x8 __attribute__((ext_vector_type(8)));
typedef bf16 bf16x4 __attribute__((ext_vector_type(4)));
typedef float f32x4 __attribute__((ext_vector_type(4)));

#define MFMA16(a, b, c) __builtin_amdgcn_mfma_f32_16x16x32_bf16((a), (b), (c), 0, 0, 0)

constexpr int D_MODEL = 768;
constexpr int NHEAD = 12;
constexpr int DK = 64;
constexpr int SEQ = 4096;
constexpr int BATCH = 2;
constexpr int MROWS = BATCH * SEQ;  // 8192

// ---------------------------------------------------------------- convert
__global__ void cvt_f32_to_bf16(const float* __restrict__ in, bf16* __restrict__ out, int n) {
    int i = (blockIdx.x * blockDim.x + threadIdx.x) * 4;
    if (i + 3 < n) {
        const float4 v = *reinterpret_cast<const float4*>(in + i);
        bf16x4 o;
        o[0] = (bf16)v.x; o[1] = (bf16)v.y; o[2] = (bf16)v.z; o[3] = (bf16)v.w;
        *reinterpret_cast<bf16x4*>(out + i) = o;
    }
}

// ---------------------------------------------------------------- GEMM  C = A * B^T + bias
// A: [M][768] bf16 (K-contiguous), Bw: [768][768] bf16 rows = output features (K-contiguous)
// MODE 0: write bf16 to [B,H,S,dk] head layout. MODE 1: write fp32 to [M][768].
template <int MODE>
__global__ __launch_bounds__(256, 2) void gemm_bt(const bf16* __restrict__ A,
                                                  const bf16* __restrict__ Bw,
                                                  const float* __restrict__ bias,
                                                  bf16* __restrict__ obf,
                                                  float* __restrict__ ofl) {
    constexpr int LDP = 88;  // stride 176B: 16B-aligned rows, 12-bank step -> ~2-way
    __shared__ bf16 Asm[128][LDP];
    __shared__ bf16 Bsm[64][LDP];
    const int tid = threadIdx.x, lane = tid & 63, wid = tid >> 6;
    const int wm = wid >> 1, wn = wid & 1;
    const int m0 = blockIdx.x * 128, n0 = blockIdx.y * 64;

    f32x4 acc[4][2];
#pragma unroll
    for (int i = 0; i < 4; i++)
#pragma unroll
        for (int j = 0; j < 2; j++) acc[i][j] = f32x4{0.f, 0.f, 0.f, 0.f};

    const int rr = tid >> 3, cc = (tid & 7) * 8;
    for (int k0 = 0; k0 < 768; k0 += 64) {
#pragma unroll
        for (int p = 0; p < 4; p++)
            *reinterpret_cast<bf16x8*>(&Asm[p * 32 + rr][cc]) =
                *reinterpret_cast<const bf16x8*>(A + (size_t)(m0 + p * 32 + rr) * 768 + k0 + cc);
#pragma unroll
        for (int p = 0; p < 2; p++)
            *reinterpret_cast<bf16x8*>(&Bsm[p * 32 + rr][cc]) =
                *reinterpret_cast<const bf16x8*>(Bw + (size_t)(n0 + p * 32 + rr) * 768 + k0 + cc);
        __syncthreads();
#pragma unroll
        for (int kk = 0; kk < 64; kk += 32) {
            const int krd = kk + ((lane >> 4) << 3);
            bf16x8 af[4], bfr[2];
#pragma unroll
            for (int i = 0; i < 4; i++)
                af[i] = *reinterpret_cast<const bf16x8*>(&Asm[wm * 64 + i * 16 + (lane & 15)][krd]);
#pragma unroll
            for (int j = 0; j < 2; j++)
                bfr[j] = *reinterpret_cast<const bf16x8*>(&Bsm[wn * 32 + j * 16 + (lane & 15)][krd]);
#pragma unroll
            for (int i = 0; i < 4; i++)
#pragma unroll
                for (int j = 0; j < 2; j++) acc[i][j] = MFMA16(af[i], bfr[j], acc[i][j]);
        }
        __syncthreads();
    }

    const int rbase = m0 + wm * 64 + ((lane >> 4) << 2);
    const int cbase = n0 + wn * 32 + (lane & 15);
#pragma unroll
    for (int i = 0; i < 4; i++) {
#pragma unroll
        for (int j = 0; j < 2; j++) {
            const int ncol = cbase + j * 16;
            const float bv = bias[ncol];
#pragma unroll
            for (int r = 0; r < 4; r++) {
                const int mrow = rbase + i * 16 + r;
                const float v = acc[i][j][r] + bv;
                if (MODE == 0) {
                    const int b = mrow >> 12, s = mrow & 4095;
                    const int h = ncol >> 6, d = ncol & 63;
                    obf[(((size_t)(b * NHEAD + h)) * SEQ + s) * DK + d] = (bf16)v;
                } else {
                    ofl[(size_t)mrow * 768 + ncol] = v;
                }
            }
        }
    }
}

// ---------------------------------------------------------------- flash attention
// grid: (SEQ/64, BATCH*NHEAD). block 256 = 4 waves, each wave owns 16 q-rows.
__global__ __launch_bounds__(256, 2) void attn_kernel(const bf16* __restrict__ Qb,
                                                      const bf16* __restrict__ Kb,
                                                      const bf16* __restrict__ Vb,
                                                      bf16* __restrict__ ctx) {
    constexpr int LDP = 88;
    __shared__ bf16 Ksm[64][LDP];
    __shared__ bf16 Vts[64][LDP];  // transposed: Vts[d][key]
    __shared__ bf16 Psm[4][16][LDP];
    const int tid = threadIdx.x, lane = tid & 63, w = tid >> 6;
    const int bh = blockIdx.y;
    const int q0 = blockIdx.x * 64;
    const bf16* Qh = Qb + (size_t)bh * SEQ * DK;
    const bf16* Kh = Kb + (size_t)bh * SEQ * DK;
    const bf16* Vh = Vb + (size_t)bh * SEQ * DK;

    // Q fragments stay in registers
    bf16x8 qf[2];
    {
        const int qr = q0 + w * 16 + (lane & 15);
        const int kc = (lane >> 4) << 3;
        qf[0] = *reinterpret_cast<const bf16x8*>(Qh + (size_t)qr * DK + kc);
        qf[1] = *reinterpret_cast<const bf16x8*>(Qh + (size_t)qr * DK + 32 + kc);
    }

    float mst[4], lst[4];
    f32x4 aco[4];
#pragma unroll
    for (int r = 0; r < 4; r++) { mst[r] = -1e30f; lst[r] = 0.f; }
#pragma unroll
    for (int f = 0; f < 4; f++) aco[f] = f32x4{0.f, 0.f, 0.f, 0.f};

    const int rr = tid >> 3, cc = (tid & 7) * 8;
    for (int k0 = 0; k0 < SEQ; k0 += 64) {
        // stage K row-major, V transposed
#pragma unroll
        for (int p = 0; p < 2; p++)
            *reinterpret_cast<bf16x8*>(&Ksm[p * 32 + rr][cc]) =
                *reinterpret_cast<const bf16x8*>(Kh + (size_t)(k0 + p * 32 + rr) * DK + cc);
#pragma unroll
        for (int p = 0; p < 2; p++) {
            bf16x8 v = *reinterpret_cast<const bf16x8*>(Vh + (size_t)(k0 + p * 32 + rr) * DK + cc);
#pragma unroll
            for (int j = 0; j < 8; j++) Vts[cc + j][p * 32 + rr] = v[j];
        }
        __syncthreads();

        // S = Q K^T for this wave's 16 q-rows x 64 keys
        f32x4 sc4[4];
#pragma unroll
        for (int f = 0; f < 4; f++) sc4[f] = f32x4{0.f, 0.f, 0.f, 0.f};
#pragma unroll
        for (int kk = 0; kk < 2; kk++) {
            const int krd = (kk << 5) + ((lane >> 4) << 3);
#pragma unroll
            for (int f = 0; f < 4; f++) {
                bf16x8 kf = *reinterpret_cast<const bf16x8*>(&Ksm[f * 16 + (lane & 15)][krd]);
                sc4[f] = MFMA16(qf[kk], kf, sc4[f]);
            }
        }
#pragma unroll
        for (int f = 0; f < 4; f++)
#pragma unroll
            for (int r = 0; r < 4; r++) sc4[f][r] *= 0.125f;  // 1/sqrt(64)

        // online softmax; lane holds rows (lane>>4)*4+r, key cols (lane&15)+16f
#pragma unroll
        for (int r = 0; r < 4; r++) {
            float tm = fmaxf(fmaxf(sc4[0][r], sc4[1][r]), fmaxf(sc4[2][r], sc4[3][r]));
            tm = fmaxf(tm, __shfl_xor(tm, 1));
            tm = fmaxf(tm, __shfl_xor(tm, 2));
            tm = fmaxf(tm, __shfl_xor(tm, 4));
            tm = fmaxf(tm, __shfl_xor(tm, 8));
            const float mnew = fmaxf(mst[r], tm);
            const float scl = __expf(mst[r] - mnew);
            mst[r] = mnew;
            float rs = 0.f;
#pragma unroll
            for (int f = 0; f < 4; f++) {
                const float p = __expf(sc4[f][r] - mnew);
                sc4[f][r] = p;
                rs += p;
            }
            rs += __shfl_xor(rs, 1);
            rs += __shfl_xor(rs, 2);
            rs += __shfl_xor(rs, 4);
            rs += __shfl_xor(rs, 8);
            lst[r] = lst[r] * scl + rs;
#pragma unroll
            for (int f = 0; f < 4; f++) aco[f][r] *= scl;
        }

        // P -> LDS (acc layout) for re-read in A-fragment layout
#pragma unroll
        for (int f = 0; f < 4; f++)
#pragma unroll
            for (int r = 0; r < 4; r++)
                Psm[w][((lane >> 4) << 2) + r][f * 16 + (lane & 15)] = (bf16)sc4[f][r];
        __syncthreads();

        // O += P V
#pragma unroll
        for (int kk = 0; kk < 2; kk++) {
            const int krd = (kk << 5) + ((lane >> 4) << 3);
            bf16x8 pf = *reinterpret_cast<const bf16x8*>(&Psm[w][lane & 15][krd]);
#pragma unroll
            for (int f = 0; f < 4; f++) {
                bf16x8 vf = *reinterpret_cast<const bf16x8*>(&Vts[f * 16 + (lane & 15)][krd]);
                aco[f] = MFMA16(pf, vf, aco[f]);
            }
        }
        __syncthreads();
    }

    const int b = bh / NHEAD, h = bh % NHEAD;
#pragma unroll
    for (int f = 0; f < 4; f++)
#pragma unroll
        for (int r = 0; r < 4; r++) {
            const int q = q0 + w * 16 + ((lane >> 4) << 2) + r;
            const int d = f * 16 + (lane & 15);
            const float v = aco[f][r] / lst[r];
            ctx[((size_t)b * SEQ + q) * D_MODEL + h * DK + d] = (bf16)v;
        }
}

// ---------------------------------------------------------------- launcher
extern "C" void kernel_launch(void* const* d_in, const int* in_sizes, int n_in,
                              void* d_out, int out_size, void* d_ws, size_t ws_size,
                              hipStream_t stream) {
    const float* x  = (const float*)d_in[0];
    const float* Wq = (const float*)d_in[1];
    const float* bq = (const float*)d_in[2];
    const float* Wk = (const float*)d_in[3];
    const float* bk = (const float*)d_in[4];
    const float* Wv = (const float*)d_in[5];
    const float* bv = (const float*)d_in[6];
    const float* Wo = (const float*)d_in[7];
    const float* bo = (const float*)d_in[8];
    float* out = (float*)d_out;

    char* ws = (char*)d_ws;
    size_t off = 0;
    auto alloc = [&](size_t bytes) { void* p = ws + off; off += (bytes + 255) & ~(size_t)255; return p; };
    bf16* xb   = (bf16*)alloc((size_t)MROWS * 768 * 2);
    bf16* Wqb  = (bf16*)alloc((size_t)768 * 768 * 2);
    bf16* Wkb  = (bf16*)alloc((size_t)768 * 768 * 2);
    bf16* Wvb  = (bf16*)alloc((size_t)768 * 768 * 2);
    bf16* Wob  = (bf16*)alloc((size_t)768 * 768 * 2);
    bf16* Qb   = (bf16*)alloc((size_t)BATCH * NHEAD * SEQ * DK * 2);
    bf16* Kb   = (bf16*)alloc((size_t)BATCH * NHEAD * SEQ * DK * 2);
    bf16* Vb   = (bf16*)alloc((size_t)BATCH * NHEAD * SEQ * DK * 2);
    bf16* ctxb = (bf16*)alloc((size_t)MROWS * 768 * 2);

    // converts
    {
        const int nx = MROWS * 768;
        cvt_f32_to_bf16<<<nx / (256 * 4), 256, 0, stream>>>(x, xb, nx);
        const int nw = 768 * 768;
        const int wb = nw / (256 * 4);
        cvt_f32_to_bf16<<<wb, 256, 0, stream>>>(Wq, Wqb, nw);
        cvt_f32_to_bf16<<<wb, 256, 0, stream>>>(Wk, Wkb, nw);
        cvt_f32_to_bf16<<<wb, 256, 0, stream>>>(Wv, Wvb, nw);
        cvt_f32_to_bf16<<<wb, 256, 0, stream>>>(Wo, Wob, nw);
    }

    // QKV projections
    dim3 gg(MROWS / 128, 768 / 64);
    gemm_bt<0><<<gg, 256, 0, stream>>>(xb, Wqb, bq, Qb, nullptr);
    gemm_bt<0><<<gg, 256, 0, stream>>>(xb, Wkb, bk, Kb, nullptr);
    gemm_bt<0><<<gg, 256, 0, stream>>>(xb, Wvb, bv, Vb, nullptr);

    // attention
    attn_kernel<<<dim3(SEQ / 64, BATCH * NHEAD), 256, 0, stream>>>(Qb, Kb, Vb, ctxb);

    // output projection
    gemm_bt<1><<<gg, 256, 0, stream>>>(ctxb, Wob, bo, nullptr, out);
}

// Round 2
// 333.287 us; speedup vs baseline: 1.6921x; 1.6921x over previous
//
#include <hip/hip_runtime.h>
#include <hip/hip_bf16.h>
#include <cstdint>

typedef __bf16 bf16;
typedef bf16 bf16x8 __attribute__((ext_vector_type(8)));
typedef float f32x4 __attribute__((ext_vector_type(4)));

#define MFMA16(a, b, c) __builtin_amdgcn_mfma_f32_16x16x32_bf16((a), (b), (c), 0, 0, 0)

constexpr int D_MODEL = 768;
constexpr int NHEAD = 12;
constexpr int DK = 64;
constexpr int SEQ = 4096;
constexpr int BATCH = 2;
constexpr int MROWS = BATCH * SEQ;  // 8192
constexpr float QSCALE = 0.125f * 1.44269504089f;  // (1/sqrt(dk)) * log2(e)

// ---------------------------------------------------------------- convert x
__global__ void cvt_f32_to_bf16(const float* __restrict__ in, bf16* __restrict__ out, int n) {
    int i = (blockIdx.x * blockDim.x + threadIdx.x) * 4;
    if (i + 3 < n) {
        const float4 v = *reinterpret_cast<const float4*>(in + i);
        bf16 o0 = (bf16)v.x, o1 = (bf16)v.y, o2 = (bf16)v.z, o3 = (bf16)v.w;
        bf16 o[4] = {o0, o1, o2, o3};
        *reinterpret_cast<uint64_t*>(out + i) = *reinterpret_cast<uint64_t*>(o);
    }
}

// ---------------------------------------------------------------- fused QKV projection
// A: [M][768] bf16. Weights fp32 [768][768] (rows = out features), converted during staging.
// sel = blockIdx.y/12: 0 -> Q (scaled, head layout), 1 -> K (head layout), 2 -> V transposed [B,H,DK,SEQ]
__global__ __launch_bounds__(256, 2) void gemm_qkv(const bf16* __restrict__ A,
                                                   const float* __restrict__ Wq,
                                                   const float* __restrict__ Wk,
                                                   const float* __restrict__ Wv,
                                                   const float* __restrict__ bq,
                                                   const float* __restrict__ bk,
                                                   const float* __restrict__ bv,
                                                   bf16* __restrict__ Qb,
                                                   bf16* __restrict__ Kb,
                                                   bf16* __restrict__ Vtb) {
    constexpr int LDP = 88;
    __shared__ bf16 Asm[128][LDP];
    __shared__ bf16 Bsm[64][LDP];
    const int tid = threadIdx.x, lane = tid & 63, wid = tid >> 6;
    const int wm = wid >> 1, wn = wid & 1;
    const int m0 = blockIdx.x * 128;
    const int sel = blockIdx.y / 12;
    const int n0 = (blockIdx.y % 12) * 64;
    const float* Bw = sel == 0 ? Wq : (sel == 1 ? Wk : Wv);
    const float* bias = sel == 0 ? bq : (sel == 1 ? bk : bv);

    f32x4 acc[4][2];
#pragma unroll
    for (int i = 0; i < 4; i++)
#pragma unroll
        for (int j = 0; j < 2; j++) acc[i][j] = f32x4{0.f, 0.f, 0.f, 0.f};

    const int rr = tid >> 3, cc = (tid & 7) * 8;
    for (int k0 = 0; k0 < 768; k0 += 64) {
#pragma unroll
        for (int p = 0; p < 4; p++)
            *reinterpret_cast<bf16x8*>(&Asm[p * 32 + rr][cc]) =
                *reinterpret_cast<const bf16x8*>(A + (size_t)(m0 + p * 32 + rr) * 768 + k0 + cc);
#pragma unroll
        for (int p = 0; p < 2; p++) {
            const float* src = Bw + (size_t)(n0 + p * 32 + rr) * 768 + k0 + cc;
            const float4 f0 = *reinterpret_cast<const float4*>(src);
            const float4 f1 = *reinterpret_cast<const float4*>(src + 4);
            bf16x8 b8;
            b8[0] = (bf16)f0.x; b8[1] = (bf16)f0.y; b8[2] = (bf16)f0.z; b8[3] = (bf16)f0.w;
            b8[4] = (bf16)f1.x; b8[5] = (bf16)f1.y; b8[6] = (bf16)f1.z; b8[7] = (bf16)f1.w;
            *reinterpret_cast<bf16x8*>(&Bsm[p * 32 + rr][cc]) = b8;
        }
        __syncthreads();
#pragma unroll
        for (int kk = 0; kk < 64; kk += 32) {
            const int krd = kk + ((lane >> 4) << 3);
            bf16x8 af[4], bfr[2];
#pragma unroll
            for (int i = 0; i < 4; i++)
                af[i] = *reinterpret_cast<const bf16x8*>(&Asm[wm * 64 + i * 16 + (lane & 15)][krd]);
#pragma unroll
            for (int j = 0; j < 2; j++)
                bfr[j] = *reinterpret_cast<const bf16x8*>(&Bsm[wn * 32 + j * 16 + (lane & 15)][krd]);
#pragma unroll
            for (int i = 0; i < 4; i++)
#pragma unroll
                for (int j = 0; j < 2; j++) acc[i][j] = MFMA16(af[i], bfr[j], acc[i][j]);
        }
        __syncthreads();
    }

    const float scale = (sel == 0) ? QSCALE : 1.0f;
    const int rbase = m0 + wm * 64 + ((lane >> 4) << 2);
    const int cbase = n0 + wn * 32 + (lane & 15);
    bf16* obf = sel == 0 ? Qb : (sel == 1 ? Kb : Vtb);
#pragma unroll
    for (int i = 0; i < 4; i++) {
#pragma unroll
        for (int j = 0; j < 2; j++) {
            const int ncol = cbase + j * 16;
            const float bv = bias[ncol];
            const int h = ncol >> 6, d = ncol & 63;
#pragma unroll
            for (int r = 0; r < 4; r++) {
                const int mrow = rbase + i * 16 + r;
                const float v = (acc[i][j][r] + bv) * scale;
                const int b = mrow >> 12, s = mrow & 4095;
                if (sel < 2) {
                    obf[(((size_t)(b * NHEAD + h)) * SEQ + s) * DK + d] = (bf16)v;
                } else {
                    obf[(((size_t)(b * NHEAD + h)) * DK + d) * SEQ + s] = (bf16)v;
                }
            }
        }
    }
}

// ---------------------------------------------------------------- out projection GEMM
__global__ __launch_bounds__(256, 2) void gemm_out(const bf16* __restrict__ A,
                                                   const float* __restrict__ Bw,
                                                   const float* __restrict__ bias,
                                                   float* __restrict__ ofl) {
    constexpr int LDP = 88;
    __shared__ bf16 Asm[128][LDP];
    __shared__ bf16 Bsm[64][LDP];
    const int tid = threadIdx.x, lane = tid & 63, wid = tid >> 6;
    const int wm = wid >> 1, wn = wid & 1;
    const int m0 = blockIdx.x * 128, n0 = blockIdx.y * 64;

    f32x4 acc[4][2];
#pragma unroll
    for (int i = 0; i < 4; i++)
#pragma unroll
        for (int j = 0; j < 2; j++) acc[i][j] = f32x4{0.f, 0.f, 0.f, 0.f};

    const int rr = tid >> 3, cc = (tid & 7) * 8;
    for (int k0 = 0; k0 < 768; k0 += 64) {
#pragma unroll
        for (int p = 0; p < 4; p++)
            *reinterpret_cast<bf16x8*>(&Asm[p * 32 + rr][cc]) =
                *reinterpret_cast<const bf16x8*>(A + (size_t)(m0 + p * 32 + rr) * 768 + k0 + cc);
#pragma unroll
        for (int p = 0; p < 2; p++) {
            const float* src = Bw + (size_t)(n0 + p * 32 + rr) * 768 + k0 + cc;
            const float4 f0 = *reinterpret_cast<const float4*>(src);
            const float4 f1 = *reinterpret_cast<const float4*>(src + 4);
            bf16x8 b8;
            b8[0] = (bf16)f0.x; b8[1] = (bf16)f0.y; b8[2] = (bf16)f0.z; b8[3] = (bf16)f0.w;
            b8[4] = (bf16)f1.x; b8[5] = (bf16)f1.y; b8[6] = (bf16)f1.z; b8[7] = (bf16)f1.w;
            *reinterpret_cast<bf16x8*>(&Bsm[p * 32 + rr][cc]) = b8;
        }
        __syncthreads();
#pragma unroll
        for (int kk = 0; kk < 64; kk += 32) {
            const int krd = kk + ((lane >> 4) << 3);
            bf16x8 af[4], bfr[2];
#pragma unroll
            for (int i = 0; i < 4; i++)
                af[i] = *reinterpret_cast<const bf16x8*>(&Asm[wm * 64 + i * 16 + (lane & 15)][krd]);
#pragma unroll
            for (int j = 0; j < 2; j++)
                bfr[j] = *reinterpret_cast<const bf16x8*>(&Bsm[wn * 32 + j * 16 + (lane & 15)][krd]);
#pragma unroll
            for (int i = 0; i < 4; i++)
#pragma unroll
                for (int j = 0; j < 2; j++) acc[i][j] = MFMA16(af[i], bfr[j], acc[i][j]);
        }
        __syncthreads();
    }

    const int rbase = m0 + wm * 64 + ((lane >> 4) << 2);
    const int cbase = n0 + wn * 32 + (lane & 15);
#pragma unroll
    for (int i = 0; i < 4; i++) {
#pragma unroll
        for (int j = 0; j < 2; j++) {
            const int ncol = cbase + j * 16;
            const float bv = bias[ncol];
#pragma unroll
            for (int r = 0; r < 4; r++) {
                const int mrow = rbase + i * 16 + r;
                ofl[(size_t)mrow * 768 + ncol] = acc[i][j][r] + bv;
            }
        }
    }
}

// ---------------------------------------------------------------- flash attention
// grid: (SEQ/128, BATCH*NHEAD). block 512 = 8 waves, each wave owns 16 q-rows. 128-key tiles.
// K staged [128 keys][64 d] stride 72; V pre-transposed, staged [64 d][128 keys] stride 136.
__global__ __launch_bounds__(512, 4) void attn_kernel(const bf16* __restrict__ Qb,
                                                      const bf16* __restrict__ Kb,
                                                      const bf16* __restrict__ Vtb,
                                                      bf16* __restrict__ ctx) {
    __shared__ bf16 Ksm[128][72];
    __shared__ bf16 Vts[64][136];
    __shared__ bf16 Psm[8][16][72];  // per-wave 16q x 64k chunk, XOR-swizzled
    const int tid = threadIdx.x, l = tid & 63, w = tid >> 6;
    const int bh = blockIdx.y;
    const int q0 = blockIdx.x * 128;
    const bf16* Qh = Qb + (size_t)bh * SEQ * DK;
    const bf16* Kh = Kb + (size_t)bh * SEQ * DK;
    const bf16* Vth = Vtb + (size_t)bh * DK * SEQ;

    const int rsel = l & 15, csel = l >> 4;

    // Q fragments in registers (already scaled by 0.125*log2e in projection)
    bf16x8 qf[2];
    {
        const int qr = q0 + w * 16 + rsel;
        const int kc = csel * 8;
        qf[0] = *reinterpret_cast<const bf16x8*>(Qh + (size_t)qr * DK + kc);
        qf[1] = *reinterpret_cast<const bf16x8*>(Qh + (size_t)qr * DK + 32 + kc);
    }

    float mst[4], lst[4];
    f32x4 aco[4];
#pragma unroll
    for (int r = 0; r < 4; r++) { mst[r] = -1e30f; lst[r] = 0.f; }
#pragma unroll
    for (int f = 0; f < 4; f++) aco[f] = f32x4{0.f, 0.f, 0.f, 0.f};

    const int kr = tid >> 3, kc8 = (tid & 7) * 8;   // K staging: rows kr, kr+64
    const int vr = tid >> 4, vc8 = (tid & 15) * 8;  // Vt staging: rows vr, vr+32

    for (int k0 = 0; k0 < SEQ; k0 += 128) {
        *reinterpret_cast<bf16x8*>(&Ksm[kr][kc8]) =
            *reinterpret_cast<const bf16x8*>(Kh + (size_t)(k0 + kr) * DK + kc8);
        *reinterpret_cast<bf16x8*>(&Ksm[kr + 64][kc8]) =
            *reinterpret_cast<const bf16x8*>(Kh + (size_t)(k0 + kr + 64) * DK + kc8);
        *reinterpret_cast<bf16x8*>(&Vts[vr][vc8]) =
            *reinterpret_cast<const bf16x8*>(Vth + (size_t)vr * SEQ + k0 + vc8);
        *reinterpret_cast<bf16x8*>(&Vts[vr + 32][vc8]) =
            *reinterpret_cast<const bf16x8*>(Vth + (size_t)(vr + 32) * SEQ + k0 + vc8);
        __syncthreads();

        // S^T fragments: 16 q-rows x 128 keys
        f32x4 sc[8];
#pragma unroll
        for (int f = 0; f < 8; f++) sc[f] = f32x4{0.f, 0.f, 0.f, 0.f};
#pragma unroll
        for (int kk = 0; kk < 2; kk++) {
            const int krd = kk * 32 + csel * 8;
#pragma unroll
            for (int f = 0; f < 8; f++) {
                bf16x8 kf = *reinterpret_cast<const bf16x8*>(&Ksm[f * 16 + rsel][krd]);
                sc[f] = MFMA16(qf[kk], kf, sc[f]);
            }
        }

        // online softmax (base-2 domain; scores pre-scaled)
#pragma unroll
        for (int r = 0; r < 4; r++) {
            float tm = sc[0][r];
#pragma unroll
            for (int f = 1; f < 8; f++) tm = fmaxf(tm, sc[f][r]);
            tm = fmaxf(tm, __shfl_xor(tm, 1));
            tm = fmaxf(tm, __shfl_xor(tm, 2));
            tm = fmaxf(tm, __shfl_xor(tm, 4));
            tm = fmaxf(tm, __shfl_xor(tm, 8));
            const float mnew = fmaxf(mst[r], tm);
            const float scl = __builtin_amdgcn_exp2f(mst[r] - mnew);
            mst[r] = mnew;
            float rs = 0.f;
#pragma unroll
            for (int f = 0; f < 8; f++) {
                const float p = __builtin_amdgcn_exp2f(sc[f][r] - mnew);
                sc[f][r] = p;
                rs += p;
            }
            rs += __shfl_xor(rs, 1);
            rs += __shfl_xor(rs, 2);
            rs += __shfl_xor(rs, 4);
            rs += __shfl_xor(rs, 8);
            lst[r] = lst[r] * scl + rs;
#pragma unroll
            for (int f = 0; f < 4; f++) aco[f][r] *= scl;
        }

        // two wave-local P/PV phases (64 keys each); DS ops are in-order per wave -> no barrier
        const int prow = csel * 4;
#pragma unroll
        for (int ph = 0; ph < 2; ph++) {
#pragma unroll
            for (int f = 0; f < 4; f++)
#pragma unroll
                for (int r = 0; r < 4; r++) {
                    const int row = prow + r;
                    Psm[w][row][(f * 16 + rsel) ^ ((row >> 3) << 4)] = (bf16)sc[ph * 4 + f][r];
                }
#pragma unroll
            for (int kkpv = 0; kkpv < 2; kkpv++) {
                const int pcol = (kkpv * 32 + csel * 8) ^ ((rsel >> 3) << 4);
                bf16x8 pf = *reinterpret_cast<const bf16x8*>(&Psm[w][rsel][pcol]);
#pragma unroll
                for (int f = 0; f < 4; f++) {
                    bf16x8 vf = *reinterpret_cast<const bf16x8*>(
                        &Vts[f * 16 + rsel][(ph * 2 + kkpv) * 32 + csel * 8]);
                    aco[f] = MFMA16(pf, vf, aco[f]);
                }
            }
        }
        __syncthreads();
    }

    const int b = bh / NHEAD, h = bh % NHEAD;
#pragma unroll
    for (int f = 0; f < 4; f++)
#pragma unroll
        for (int r = 0; r < 4; r++) {
            const int q = q0 + w * 16 + csel * 4 + r;
            const int d = f * 16 + rsel;
            ctx[((size_t)b * SEQ + q) * D_MODEL + h * DK + d] = (bf16)(aco[f][r] / lst[r]);
        }
}

// ---------------------------------------------------------------- launcher
extern "C" void kernel_launch(void* const* d_in, const int* in_sizes, int n_in,
                              void* d_out, int out_size, void* d_ws, size_t ws_size,
                              hipStream_t stream) {
    const float* x  = (const float*)d_in[0];
    const float* Wq = (const float*)d_in[1];
    const float* bq = (const float*)d_in[2];
    const float* Wk = (const float*)d_in[3];
    const float* bk = (const float*)d_in[4];
    const float* Wv = (const float*)d_in[5];
    const float* bv = (const float*)d_in[6];
    const float* Wo = (const float*)d_in[7];
    const float* bo = (const float*)d_in[8];
    float* out = (float*)d_out;

    char* ws = (char*)d_ws;
    size_t off = 0;
    auto alloc = [&](size_t bytes) { void* p = ws + off; off += (bytes + 255) & ~(size_t)255; return p; };
    bf16* xb   = (bf16*)alloc((size_t)MROWS * 768 * 2);
    bf16* Qb   = (bf16*)alloc((size_t)BATCH * NHEAD * SEQ * DK * 2);
    bf16* Kb   = (bf16*)alloc((size_t)BATCH * NHEAD * SEQ * DK * 2);
    bf16* Vtb  = (bf16*)alloc((size_t)BATCH * NHEAD * SEQ * DK * 2);
    bf16* ctxb = (bf16*)alloc((size_t)MROWS * 768 * 2);

    const int nx = MROWS * 768;
    cvt_f32_to_bf16<<<nx / (256 * 4), 256, 0, stream>>>(x, xb, nx);

    gemm_qkv<<<dim3(MROWS / 128, 36), 256, 0, stream>>>(xb, Wq, Wk, Wv, bq, bk, bv, Qb, Kb, Vtb);

    attn_kernel<<<dim3(SEQ / 128, BATCH * NHEAD), 512, 0, stream>>>(Qb, Kb, Vtb, ctxb);

    gemm_out<<<dim3(MROWS / 128, 768 / 64), 256, 0, stream>>>(ctxb, Wo, bo, out);
}